// Round 11
// baseline (183.892 us; speedup 1.0000x reference)
//
#include <hip/hip_runtime.h>
#include <hip/hip_bf16.h>
#include <cmath>

#define B_   2
#define S_   2048
#define D_   768
#define H_   12
#define HD_  64
#define WIN_ 64

typedef __bf16 bf16x8 __attribute__((ext_vector_type(8)));
typedef __bf16 bf16x4 __attribute__((ext_vector_type(4)));
typedef float  f32x4  __attribute__((ext_vector_type(4)));
typedef unsigned int u32;

__device__ __forceinline__ void async_ld16(const void* g, void* l) {
    __builtin_amdgcn_global_load_lds(
        (__attribute__((address_space(1))) void*)(size_t)g,
        (__attribute__((address_space(3))) void*)(u32)(size_t)l,
        16, 0, 0);
}

// ---------------------------------------------------------------------------
// fp32 -> bf16 convert for hs / Wqkv / Wo (one pass)
// ---------------------------------------------------------------------------
#define NHS (B_ * S_ * D_)        // 3145728
#define NWQ (3 * D_ * D_)         // 1769472
#define NWO (D_ * D_)             //  589824

__global__ __launch_bounds__(256) void to_bf16_3(const float* __restrict__ a,
                                                 const float* __restrict__ b,
                                                 const float* __restrict__ c,
                                                 __bf16* __restrict__ oa,
                                                 __bf16* __restrict__ ob,
                                                 __bf16* __restrict__ oc) {
    const int NA = NHS / 4, NB = NWQ / 4;
    int v = blockIdx.x * 256 + threadIdx.x;
    const float* src; __bf16* dst; int idx;
    if (v < NA)           { src = a; dst = oa; idx = v; }
    else if (v < NA + NB) { src = b; dst = ob; idx = v - NA; }
    else                  { src = c; dst = oc; idx = v - NA - NB; }
    float4 x = ((const float4*)src)[idx];
    bf16x4 y = { (__bf16)x.x, (__bf16)x.y, (__bf16)x.z, (__bf16)x.w };
    *(bf16x4*)(dst + (size_t)idx * 4) = y;
}

// ---------------------------------------------------------------------------
// GEMM, round-21: register-direct fragments with NAMED scalar frag vars.
// R10 falsified the fixed-phase-latency model (BK=64 didn't help): staging
// is THROUGHPUT-limited.  The only untested design is register-direct
// (R3/R4 failed mechanically: VGPR_Count=84 proved frag arrays lived in
// scratch; addressing itself passed correctness).  Fix the failure mode:
// no fragment arrays anywhere -- 16 individually-named bf16x8 variables
// (two sets, depth-2 dbuf), touched only via macros with literal names.
// Loop: MM(x) -> LD(x,k+2) -> MM(y) -> LD(y,k+3): X-loads issue under Y's
// MFMAs; compiler emits exact counted vmcnt on register deps (T4 free).
// No LDS in the K-loop at all.  Per-wave 64x64 tile over full K (24 it).
// g1: 576 blocks x 4 waves.  g2: 768 SINGLE-WAVE 64-thread blocks = 3
// blocks/CU (fixes its 0.75 blk/CU idle-machine problem).
// Budget: 64 frag VGPR + 64 acc AGPR + addr ~= 155 unified -> 3 waves/SIMD.
// Epilogues: R3's (correctness-proven), per-wave private LDS bounce.
// MODE 0: fp32 C.  MODE 1: fused RoPE -> qkv bf16 (n<1536); v -> vt bf16^T.
// ---------------------------------------------------------------------------
#define LD8(A0, A1, A2, A3, Bb0, Bb1, Bb2, Bb3, kk)                           \
    { const size_t ko_ = (size_t)(kk) * 32;                                   \
      A0  = *(const bf16x8*)(Ap + ko_);                                       \
      A1  = *(const bf16x8*)(Ap + rstep + ko_);                               \
      A2  = *(const bf16x8*)(Ap + 2 * rstep + ko_);                           \
      A3  = *(const bf16x8*)(Ap + 3 * rstep + ko_);                           \
      Bb0 = *(const bf16x8*)(Bp + ko_);                                       \
      Bb1 = *(const bf16x8*)(Bp + rstep + ko_);                               \
      Bb2 = *(const bf16x8*)(Bp + 2 * rstep + ko_);                           \
      Bb3 = *(const bf16x8*)(Bp + 3 * rstep + ko_); }

#define MM16(A0, A1, A2, A3, Bb0, Bb1, Bb2, Bb3)                              \
    { acc[0][0] = __builtin_amdgcn_mfma_f32_16x16x32_bf16(A0, Bb0, acc[0][0], 0, 0, 0); \
      acc[0][1] = __builtin_amdgcn_mfma_f32_16x16x32_bf16(A0, Bb1, acc[0][1], 0, 0, 0); \
      acc[0][2] = __builtin_amdgcn_mfma_f32_16x16x32_bf16(A0, Bb2, acc[0][2], 0, 0, 0); \
      acc[0][3] = __builtin_amdgcn_mfma_f32_16x16x32_bf16(A0, Bb3, acc[0][3], 0, 0, 0); \
      acc[1][0] = __builtin_amdgcn_mfma_f32_16x16x32_bf16(A1, Bb0, acc[1][0], 0, 0, 0); \
      acc[1][1] = __builtin_amdgcn_mfma_f32_16x16x32_bf16(A1, Bb1, acc[1][1], 0, 0, 0); \
      acc[1][2] = __builtin_amdgcn_mfma_f32_16x16x32_bf16(A1, Bb2, acc[1][2], 0, 0, 0); \
      acc[1][3] = __builtin_amdgcn_mfma_f32_16x16x32_bf16(A1, Bb3, acc[1][3], 0, 0, 0); \
      acc[2][0] = __builtin_amdgcn_mfma_f32_16x16x32_bf16(A2, Bb0, acc[2][0], 0, 0, 0); \
      acc[2][1] = __builtin_amdgcn_mfma_f32_16x16x32_bf16(A2, Bb1, acc[2][1], 0, 0, 0); \
      acc[2][2] = __builtin_amdgcn_mfma_f32_16x16x32_bf16(A2, Bb2, acc[2][2], 0, 0, 0); \
      acc[2][3] = __builtin_amdgcn_mfma_f32_16x16x32_bf16(A2, Bb3, acc[2][3], 0, 0, 0); \
      acc[3][0] = __builtin_amdgcn_mfma_f32_16x16x32_bf16(A3, Bb0, acc[3][0], 0, 0, 0); \
      acc[3][1] = __builtin_amdgcn_mfma_f32_16x16x32_bf16(A3, Bb1, acc[3][1], 0, 0, 0); \
      acc[3][2] = __builtin_amdgcn_mfma_f32_16x16x32_bf16(A3, Bb2, acc[3][2], 0, 0, 0); \
      acc[3][3] = __builtin_amdgcn_mfma_f32_16x16x32_bf16(A3, Bb3, acc[3][3], 0, 0, 0); }

template <int MODE, int NW>
__global__ __launch_bounds__(NW * 64, 2) void gemm_d(const __bf16* __restrict__ A,
                                                     const __bf16* __restrict__ Bw,
                                                     float* __restrict__ C,
                                                     __bf16* __restrict__ qkv,
                                                     __bf16* __restrict__ vt,
                                                     const int* __restrict__ pos,
                                                     int M, int N, int K) {
    __shared__ __attribute__((aligned(16))) char esmem[NW][8704];

    const int tid  = threadIdx.x;
    const int w    = tid >> 6;
    const int lane = tid & 63;
    const int id = blockIdx.x;
    const int m0 = (id & 63) << 6;               // m fastest: XCD partitioning
    const int n0 = ((id >> 6) * NW + w) << 6;    // per-wave n panel
    const int fr = lane & 15, fq = lane >> 4;

    const __bf16* Ap = A  + (size_t)(m0 + fr) * K + fq * 8;
    const __bf16* Bp = Bw + (size_t)(n0 + fr) * K + fq * 8;
    const size_t rstep = (size_t)16 * K;         // 16 rows

    f32x4 acc[4][4] = {};
    bf16x8 xa0, xa1, xa2, xa3, xb0, xb1, xb2, xb3;   // set X (even tiles)
    bf16x8 ya0, ya1, ya2, ya3, yb0, yb1, yb2, yb3;   // set Y (odd tiles)

    const int nkw = K >> 5;                      // 24 (even)

    LD8(xa0, xa1, xa2, xa3, xb0, xb1, xb2, xb3, 0)
    LD8(ya0, ya1, ya2, ya3, yb0, yb1, yb2, yb3, 1)
    for (int kk = 0; kk + 2 < nkw; kk += 2) {
        MM16(xa0, xa1, xa2, xa3, xb0, xb1, xb2, xb3)          // tile kk
        LD8(xa0, xa1, xa2, xa3, xb0, xb1, xb2, xb3, kk + 2)   // prefetch
        MM16(ya0, ya1, ya2, ya3, yb0, yb1, yb2, yb3)          // tile kk+1
        LD8(ya0, ya1, ya2, ya3, yb0, yb1, yb2, yb3, kk + 3)   // prefetch
    }
    MM16(xa0, xa1, xa2, xa3, xb0, xb1, xb2, xb3)              // tile nkw-2
    MM16(ya0, ya1, ya2, ya3, yb0, yb1, yb2, yb3)              // tile nkw-1

    // ---- per-wave epilogue, coalesced via private LDS bounce (R3-proven) --
    if (MODE == 0) {
        // fp32 [32][65] bounce, two 32-row halves
        float* eL = (float*)esmem[w];
        #pragma unroll
        for (int half = 0; half < 2; ++half) {
            #pragma unroll
            for (int ti = 0; ti < 2; ++ti)
                #pragma unroll
                for (int tj = 0; tj < 4; ++tj)
                    #pragma unroll
                    for (int r = 0; r < 4; ++r)
                        eL[(ti * 16 + fq * 4 + r) * 65 + tj * 16 + fr] =
                            acc[half * 2 + ti][tj][r];
            #pragma unroll
            for (int p = 0; p < 8; ++p) {
                const int rc = p * 4 + (lane >> 4), ch = lane & 15;
                f32x4 vv = *(const f32x4*)(eL + rc * 65 + ch * 4);
                *(f32x4*)(C + (size_t)(m0 + half * 32 + rc) * N + n0 + ch * 4) = vv;
            }
        }
    } else if (n0 < 2 * D_) {
        // fused RoPE on fp32 acc, then bf16 coalesced store
        const float invf0 = __powf(10000.0f, -(float)fr * (1.0f / 32.0f));
        const float invf1 = __powf(10000.0f, -(float)(16 + fr) * (1.0f / 32.0f));
        #pragma unroll
        for (int ti = 0; ti < 4; ++ti)
            #pragma unroll
            for (int r = 0; r < 4; ++r) {
                const int row = m0 + ti * 16 + fq * 4 + r;
                const float p = (float)pos[row];
                float s0, c0, s1, c1;
                __sincosf(p * invf0, &s0, &c0);
                __sincosf(p * invf1, &s1, &c1);
                const float x0 = acc[ti][0][r], x1 = acc[ti][2][r];
                acc[ti][0][r] = x0 * c0 - x1 * s0;
                acc[ti][2][r] = x1 * c0 + x0 * s0;
                const float y0 = acc[ti][1][r], y1 = acc[ti][3][r];
                acc[ti][1][r] = y0 * c1 - y1 * s1;
                acc[ti][3][r] = y1 * c1 + y0 * s1;
            }
        __bf16* eL = (__bf16*)esmem[w];           // [64][68] bf16
        #pragma unroll
        for (int ti = 0; ti < 4; ++ti)
            #pragma unroll
            for (int tj = 0; tj < 4; ++tj)
                #pragma unroll
                for (int r = 0; r < 4; ++r)
                    eL[(ti * 16 + fq * 4 + r) * 68 + tj * 16 + fr] = (__bf16)acc[ti][tj][r];
        #pragma unroll
        for (int p = 0; p < 8; ++p) {
            const int rq = p * 8 + (lane >> 3), ch = lane & 7;
            bf16x8 vv = *(const bf16x8*)(eL + rq * 68 + ch * 8);
            *(bf16x8*)(qkv + (size_t)(m0 + rq) * (2 * D_) + n0 + ch * 8) = vv;
        }
    } else {
        // v -> vt[b][h][d][token], transposed in LDS, coalesced 128-B rows
        const int h = (n0 - 2 * D_) >> 6;
        const int bb = m0 >> 11, t0 = m0 & (S_ - 1);
        __bf16* eL = (__bf16*)esmem[w];           // [64 d][68 tok] bf16
        #pragma unroll
        for (int ti = 0; ti < 4; ++ti)
            #pragma unroll
            for (int tj = 0; tj < 4; ++tj)
                #pragma unroll
                for (int r = 0; r < 4; ++r)
                    eL[(tj * 16 + fr) * 68 + ti * 16 + fq * 4 + r] = (__bf16)acc[ti][tj][r];
        const size_t vb = (size_t)((bb * H_ + h) * HD_) * S_ + t0;
        #pragma unroll
        for (int p = 0; p < 8; ++p) {
            const int d = p * 8 + (lane >> 3), ch = lane & 7;
            bf16x8 vv = *(const bf16x8*)(eL + d * 68 + ch * 8);
            *(bf16x8*)(vt + vb + (size_t)d * S_ + ch * 8) = vv;
        }
    }
}

// ---------------------------------------------------------------------------
// MFMA banded attention (round-9 form: conflict-free LDS via the verified
// chunk-permute/swizzle algebra; values identical, placement swizzled).
// ---------------------------------------------------------------------------
__global__ __launch_bounds__(256) void attn_mfma(const __bf16* __restrict__ qkv,
                                                 const __bf16* __restrict__ vt,
                                                 __bf16* __restrict__ outb) {
    __shared__ __attribute__((aligned(16))) __bf16 smem[24576];  // 48 KB
    __bf16* Ks  = smem;
    __bf16* Vts = smem + 12288;

    const int i0  = blockIdx.x * 64;
    const int h   = blockIdx.y;
    const int b   = blockIdx.z;
    const int tid = threadIdx.x;
    const int w = tid >> 6, lane = tid & 63;
    const int fr = lane & 15, fq = lane >> 4;
    const int sw = (fq + (fr >> 1)) & 3;     // swizzled chunk-in-row
    const int wq0 = w * 16;

    #pragma unroll
    for (int i = 0; i < 6; ++i) {
        int c = i * 256 + tid;
        int ks = (i >= 3);
        int rem = c - ks * 768;
        int ccp = rem & 3, row = rem >> 2;
        int cc = (ccp - (row >> 1)) & 3;                     // source chunk permute
        int j = i0 - 64 + row; j = min(max(j, 0), S_ - 1);   // clamped; masked later
        async_ld16(qkv + ((size_t)b * S_ + j) * (2 * D_) + D_ + h * HD_ + ks * 32 + cc * 8,
                   Ks + c * 8);
    }
    const size_t vbase = (size_t)((b * H_ + h) * HD_) * S_;
    #pragma unroll
    for (int i = 0; i < 6; ++i) {
        int c = i * 256 + tid;
        int ks = c >> 8, rem = c & 255, d = rem >> 2, ccp = rem & 3;
        int cc = (ccp - (d >> 1)) & 3;                       // source chunk permute
        int key = i0 - 64 + ks * 32 + cc * 8;
        key = min(max(key, 0), S_ - 8);                      // clamped; masked later
        async_ld16(vt + vbase + (size_t)d * S_ + key, Vts + c * 8);
    }

    const size_t qrow = ((size_t)b * S_ + i0 + wq0 + fr) * (2 * D_) + h * HD_;
    bf16x8 aq[2];
    aq[0] = *(const bf16x8*)(qkv + qrow + fq * 8);
    aq[1] = *(const bf16x8*)(qkv + qrow + 32 + fq * 8);

    __syncthreads();

    f32x4 sc[12] = {};
    #pragma unroll
    for (int nt = 0; nt < 12; ++nt) {
        #pragma unroll
        for (int ks = 0; ks < 2; ++ks) {
            bf16x8 bk = *(const bf16x8*)(Ks + (ks * 192 + nt * 16 + fr) * 32 + sw * 8);
            sc[nt] = __builtin_amdgcn_mfma_f32_16x16x32_bf16(aq[ks], bk, sc[nt], 0, 0, 0);
        }
    }

    float mx[4] = { -1e30f, -1e30f, -1e30f, -1e30f };
    #pragma unroll
    for (int nt = 0; nt < 12; ++nt) {
        const int jr = nt * 16 + fr;
        const int j  = i0 - 64 + jr;
        const bool jv = (j >= 0) && (j < S_);
        #pragma unroll
        for (int r = 0; r < 4; ++r) {
            const int ir = wq0 + fq * 4 + r + 64;
            const int dd = ir - jr;
            const bool v = jv && (dd <= WIN_) && (dd >= -WIN_);
            sc[nt][r] = v ? sc[nt][r] * 0.125f : -1e30f;
            mx[r] = fmaxf(mx[r], sc[nt][r]);
        }
    }
    #pragma unroll
    for (int r = 0; r < 4; ++r)
        #pragma unroll
        for (int off = 1; off < 16; off <<= 1)
            mx[r] = fmaxf(mx[r], __shfl_xor(mx[r], off, 64));

    float sm[4] = { 0.f, 0.f, 0.f, 0.f };
    #pragma unroll
    for (int nt = 0; nt < 12; ++nt)
        #pragma unroll
        for (int r = 0; r < 4; ++r) {
            float e = __expf(sc[nt][r] - mx[r]);
            sc[nt][r] = e;
            sm[r] += e;
        }
    #pragma unroll
    for (int r = 0; r < 4; ++r) {
        #pragma unroll
        for (int off = 1; off < 16; off <<= 1)
            sm[r] += __shfl_xor(sm[r], off, 64);
        sm[r] = 1.0f / sm[r];
    }

    __syncthreads();

    __bf16* Pw = Ks + w * 3072;
    #pragma unroll
    for (int nt = 0; nt < 12; ++nt) {
        const int ks = nt >> 1, kk = (nt & 1) * 16 + fr;
        const int kc = kk >> 3, kj = kk & 7;
        #pragma unroll
        for (int r = 0; r < 4; ++r) {
            // row = ks*16 + fq*4 + r; place chunk kc at ((kc + (row>>1)) & 3)
            const int pc = (kc + 2 * fq + (r >> 1)) & 3;
            Pw[(ks * 16 + fq * 4 + r) * 32 + pc * 8 + kj] = (__bf16)(sc[nt][r] * sm[r]);
        }
    }

    f32x4 oacc[4] = {};
    #pragma unroll
    for (int ks = 0; ks < 6; ++ks) {
        bf16x8 ap = *(const bf16x8*)(Pw + (ks * 16 + fr) * 32 + sw * 8);
        #pragma unroll
        for (int nt2 = 0; nt2 < 4; ++nt2) {
            bf16x8 bv = *(const bf16x8*)(Vts + (ks * 64 + nt2 * 16 + fr) * 32 + sw * 8);
            oacc[nt2] = __builtin_amdgcn_mfma_f32_16x16x32_bf16(ap, bv, oacc[nt2], 0, 0, 0);
        }
    }

    // O via per-wave LDS bounce (reuse Pw region) -> coalesced 128-B rows
    #pragma unroll
    for (int nt2 = 0; nt2 < 4; ++nt2)
        #pragma unroll
        for (int r = 0; r < 4; ++r)
            Pw[(fq * 4 + r) * 68 + nt2 * 16 + fr] = (__bf16)oacc[nt2][r];
    #pragma unroll
    for (int p = 0; p < 2; ++p) {
        const int q = p * 8 + (lane >> 3), ch = lane & 7;
        bf16x8 vv = *(const bf16x8*)(Pw + q * 68 + ch * 8);
        *(bf16x8*)(outb + ((size_t)b * S_ + i0 + wq0 + q) * D_ + h * HD_ + ch * 8) = vv;
    }
}

// ---------------------------------------------------------------------------
extern "C" void kernel_launch(void* const* d_in, const int* in_sizes, int n_in,
                              void* d_out, int out_size, void* d_ws, size_t ws_size,
                              hipStream_t stream) {
    const float* hs   = (const float*)d_in[0];
    const float* wqkv = (const float*)d_in[1];
    const float* wo   = (const float*)d_in[2];
    const int*   pos  = (const int*)d_in[4];
    float* out = (float*)d_out;

    __bf16* base    = (__bf16*)d_ws;
    __bf16* hs_bf   = base;                          // 3,145,728
    __bf16* wqkv_bf = hs_bf + NHS;                   // 1,769,472
    __bf16* wo_bf   = wqkv_bf + NWQ;                 //   589,824
    __bf16* qkv     = wo_bf + NWO;                   // 4096*1536
    __bf16* vt      = qkv + (size_t)(B_ * S_) * (2 * D_);   // 2*12*64*2048
    __bf16* attn_bf = vt + (size_t)B_ * H_ * HD_ * S_;      // 4096*768

    // 1) fp32 -> bf16
    to_bf16_3<<<(NHS + NWQ + NWO) / 1024, 256, 0, stream>>>(
        hs, wqkv, wo, hs_bf, wqkv_bf, wo_bf);

    // 2) qkv = hs @ Wqkv^T  (RoPE fused -> qkv bf16; v -> vt transposed)
    //    register-direct named-scalar frags, 576 blocks x 4 waves
    gemm_d<1, 4><<<dim3(64 * (3 * D_ / 256)), 256, 0, stream>>>(
        hs_bf, wqkv_bf, nullptr, qkv, vt, pos, B_ * S_, 3 * D_, D_);

    // 3) banded MFMA attention (conflict-free LDS)
    attn_mfma<<<dim3(S_ / 64, H_, B_), 256, 0, stream>>>(qkv, vt, attn_bf);

    // 4) out = attn @ Wo^T (fp32 out)  768 single-wave blocks = 3 blocks/CU
    gemm_d<0, 1><<<dim3(64 * (D_ / 64)), 64, 0, stream>>>(
        attn_bf, wo_bf, out, nullptr, nullptr, nullptr, B_ * S_, D_, D_);
}

// Round 12
// 146.202 us; speedup vs baseline: 1.2578x; 1.2578x over previous
//
#include <hip/hip_runtime.h>
#include <hip/hip_bf16.h>
#include <cmath>

#define B_   2
#define S_   2048
#define D_   768
#define H_   12
#define HD_  64
#define WIN_ 64

typedef __bf16 bf16x8 __attribute__((ext_vector_type(8)));
typedef __bf16 bf16x4 __attribute__((ext_vector_type(4)));
typedef float  f32x4  __attribute__((ext_vector_type(4)));
typedef unsigned int u32;

__device__ __forceinline__ void async_ld16(const void* g, void* l) {
    __builtin_amdgcn_global_load_lds(
        (__attribute__((address_space(1))) void*)(size_t)g,
        (__attribute__((address_space(3))) void*)(u32)(size_t)l,
        16, 0, 0);
}

// ---------------------------------------------------------------------------
// fp32 -> bf16 convert for hs / Wqkv / Wo (one pass)
// ---------------------------------------------------------------------------
#define NHS (B_ * S_ * D_)        // 3145728
#define NWQ (3 * D_ * D_)         // 1769472
#define NWO (D_ * D_)             //  589824

__global__ __launch_bounds__(256) void to_bf16_3(const float* __restrict__ a,
                                                 const float* __restrict__ b,
                                                 const float* __restrict__ c,
                                                 __bf16* __restrict__ oa,
                                                 __bf16* __restrict__ ob,
                                                 __bf16* __restrict__ oc) {
    const int NA = NHS / 4, NB = NWQ / 4;
    int v = blockIdx.x * 256 + threadIdx.x;
    const float* src; __bf16* dst; int idx;
    if (v < NA)           { src = a; dst = oa; idx = v; }
    else if (v < NA + NB) { src = b; dst = ob; idx = v - NA; }
    else                  { src = c; dst = oc; idx = v - NA - NB; }
    float4 x = ((const float4*)src)[idx];
    bf16x4 y = { (__bf16)x.x, (__bf16)x.y, (__bf16)x.z, (__bf16)x.w };
    *(bf16x4*)(dst + (size_t)idx * 4) = y;
}

// ---------------------------------------------------------------------------
// GEMM, round-22: IN-BLOCK SPLIT-K=2 on the R5 structure.
// Budget identity (R3/R5/R11): dur = 43.5us fill tax + gemms + ~5us rest.
// The gemms (43+43) are the whole game.  Per-block path = #phases x
// (cost ~ bytes staged) at ~10 B/cyc per block DMA stream (m97-consistent).
// Lever: 512 threads = 2 wave-groups; group g owns K-half [g*384,(g+1)*384)
// with its OWN 4 statically-named LDS buffer pairs (64 KB total), running
// the verbatim R5 2-phase schedule -- 12 phases instead of 24, both groups
// concurrent (2x DMA streams per block), total staged bytes unchanged.
// Identical __syncthreads cadence for both groups.  After the K-loop:
// waves 4-7 park acc partials in LDS (lane-aligned f32x4, R0-proven),
// barrier, waves 0-3 add, barrier, then unchanged R5 epilogues on waves
// 0-3 (RoPE after the sum -> correct).  Alias sets for the compiler stay
// disjoint: phase-0 bufs in {sA0g0,sA0g1}, phase-1 in {sA1g0,sA1g1}.
// MODE 0: fp32 C.  MODE 1: fused RoPE -> qkv bf16 (n<1536); v -> vt bf16^T.
// ---------------------------------------------------------------------------
#define GSTAGE2(DA, DB, kk)                                                   \
    { const int k0_ = (kk) << 5;                                              \
      _Pragma("unroll")                                                       \
      for (int i_ = 0; i_ < 2; ++i_) {                                        \
          const int c_ = i_ * 256 + tg;                                       \
          const int row_ = c_ >> 2;                                           \
          const int cc_ = ((c_ & 3) - (row_ >> 1)) & 3;                       \
          async_ld16(A  + (size_t)(m0 + row_) * K + k0_ + cc_ * 8, (DA) + c_ * 8); \
          async_ld16(Bw + (size_t)(n0 + row_) * K + k0_ + cc_ * 8, (DB) + c_ * 8); \
      } }

#define TCOMP(SA, SB)                                                         \
    { bf16x8 af_[4], bf_[4];                                                  \
      _Pragma("unroll")                                                       \
      for (int t_ = 0; t_ < 4; ++t_) {                                        \
          af_[t_] = *(const bf16x8*)((SA) + (wr64 + t_ * 16 + fr) * 32 + sw * 8); \
          bf_[t_] = *(const bf16x8*)((SB) + (wc64 + t_ * 16 + fr) * 32 + sw * 8); \
      }                                                                       \
      _Pragma("unroll")                                                       \
      for (int ti_ = 0; ti_ < 4; ++ti_)                                       \
          _Pragma("unroll")                                                   \
          for (int tj_ = 0; tj_ < 4; ++tj_)                                   \
              acc[ti_][tj_] = __builtin_amdgcn_mfma_f32_16x16x32_bf16(        \
                  af_[ti_], bf_[tj_], acc[ti_][tj_], 0, 0, 0); }

template <int MODE>
__global__ __launch_bounds__(512) void gemm_k2(const __bf16* __restrict__ A,
                                               const __bf16* __restrict__ Bw,
                                               float* __restrict__ C,
                                               __bf16* __restrict__ qkv,
                                               __bf16* __restrict__ vt,
                                               const int* __restrict__ pos,
                                               int M, int N, int K) {
    __shared__ __attribute__((aligned(16))) __bf16 sA0g0[4096];  // 128x32 each
    __shared__ __attribute__((aligned(16))) __bf16 sB0g0[4096];
    __shared__ __attribute__((aligned(16))) __bf16 sA1g0[4096];
    __shared__ __attribute__((aligned(16))) __bf16 sB1g0[4096];
    __shared__ __attribute__((aligned(16))) __bf16 sA0g1[4096];
    __shared__ __attribute__((aligned(16))) __bf16 sB0g1[4096];
    __shared__ __attribute__((aligned(16))) __bf16 sA1g1[4096];
    __shared__ __attribute__((aligned(16))) __bf16 sB1g1[4096];

    const int tid  = threadIdx.x;
    const int w    = tid >> 6;              // 0..7
    const int g    = w >> 2;                // K-half group
    const int w2   = w & 3;                 // wave-in-group (quadrant owner)
    const int tg   = tid & 255;             // thread-in-group
    const int lane = tid & 63;
    const int id = blockIdx.x;
    const int m0 = (id & 31) << 7;          // m fastest: XCD partitioning
    const int n0 = (id >> 5) << 7;
    const int fr = lane & 15, fq = lane >> 4;
    const int sw = (fq + (fr >> 1)) & 3;    // swizzled chunk-in-row (verified)
    const int wr64 = (w2 >> 1) * 64, wc64 = (w2 & 1) * 64;

    // group-local buffer pointers (disjoint sets per phase parity)
    __bf16* myA0 = g ? sA0g1 : sA0g0;
    __bf16* myB0 = g ? sB0g1 : sB0g0;
    __bf16* myA1 = g ? sA1g1 : sA1g0;
    __bf16* myB1 = g ? sB1g1 : sB1g0;

    f32x4 acc[4][4] = {};

    const int kb = g * 12;                  // 12 BK-32 phases per group

    GSTAGE2(myA0, myB0, kb + 0)
    __syncthreads();                        // phase-0 DMA drained (both groups)
    for (int t = 0; t + 2 < 12; t += 2) {
        GSTAGE2(myA1, myB1, kb + t + 1)     // issue next phase (odd)
        TCOMP(myA0, myB0)                   // compute even phase
        __syncthreads();                    // implicit vmcnt(0): odd landed
        GSTAGE2(myA0, myB0, kb + t + 2)     // issue next phase (even)
        TCOMP(myA1, myB1)                   // compute odd phase
        __syncthreads();
    }
    GSTAGE2(myA1, myB1, kb + 11)
    TCOMP(myA0, myB0)                       // phase 10
    __syncthreads();
    TCOMP(myA1, myB1)                       // phase 11
    __syncthreads();                        // all K-loop LDS reads retired

    // ---- in-block split-K reduce: waves 4-7 park, waves 0-3 add ----
    {
        float* pA = (w2 == 0) ? (float*)sA0g0 : (w2 == 1) ? (float*)sA1g0
                  : (w2 == 2) ? (float*)sA0g1 : (float*)sA1g1;
        float* pB = (w2 == 0) ? (float*)sB0g0 : (w2 == 1) ? (float*)sB1g0
                  : (w2 == 2) ? (float*)sB0g1 : (float*)sB1g1;
        if (w >= 4) {
            #pragma unroll
            for (int ti = 0; ti < 2; ++ti)
                #pragma unroll
                for (int tj = 0; tj < 4; ++tj)
                    *(f32x4*)(pA + (ti * 4 + tj) * 256 + lane * 4) = acc[ti][tj];
            #pragma unroll
            for (int ti = 2; ti < 4; ++ti)
                #pragma unroll
                for (int tj = 0; tj < 4; ++tj)
                    *(f32x4*)(pB + ((ti - 2) * 4 + tj) * 256 + lane * 4) = acc[ti][tj];
        }
        __syncthreads();
        if (w < 4) {
            #pragma unroll
            for (int ti = 0; ti < 2; ++ti)
                #pragma unroll
                for (int tj = 0; tj < 4; ++tj)
                    acc[ti][tj] += *(const f32x4*)(pA + (ti * 4 + tj) * 256 + lane * 4);
            #pragma unroll
            for (int ti = 2; ti < 4; ++ti)
                #pragma unroll
                for (int tj = 0; tj < 4; ++tj)
                    acc[ti][tj] += *(const f32x4*)(pB + ((ti - 2) * 4 + tj) * 256 + lane * 4);
        }
        __syncthreads();
    }
    if (w >= 4) return;

    // ---- per-wave epilogue in private 8 KB region (overlays staging) ----
    __bf16* eW = (w == 0) ? sA0g0 : (w == 1) ? sA1g0 : (w == 2) ? sA0g1 : sA1g1;
    const int mm0 = m0 + wr64, nn0 = n0 + wc64;

    if (MODE == 0) {
        float* eL = (float*)eW;             // [32][64] fp32 = 8192 B, 2 passes
        #pragma unroll
        for (int half = 0; half < 2; ++half) {
            #pragma unroll
            for (int ti = 0; ti < 2; ++ti)
                #pragma unroll
                for (int tj = 0; tj < 4; ++tj)
                    #pragma unroll
                    for (int r = 0; r < 4; ++r)
                        eL[(ti * 16 + fq * 4 + r) * 64 + tj * 16 + fr] =
                            acc[half * 2 + ti][tj][r];
            #pragma unroll
            for (int p = 0; p < 8; ++p) {
                const int rc = p * 4 + (lane >> 4), ch = lane & 15;
                f32x4 vv = *(const f32x4*)(eL + rc * 64 + ch * 4);
                *(f32x4*)(C + (size_t)(mm0 + half * 32 + rc) * N + nn0 + ch * 4) = vv;
            }
        }
    } else if (nn0 < 2 * D_) {
        // fused RoPE on summed fp32 acc, then bf16 coalesced store (2 passes)
        const float invf0 = __powf(10000.0f, -(float)fr * (1.0f / 32.0f));
        const float invf1 = __powf(10000.0f, -(float)(16 + fr) * (1.0f / 32.0f));
        #pragma unroll
        for (int ti = 0; ti < 4; ++ti)
            #pragma unroll
            for (int r = 0; r < 4; ++r) {
                const int row = mm0 + ti * 16 + fq * 4 + r;
                const float p = (float)pos[row];
                float s0, c0, s1, c1;
                __sincosf(p * invf0, &s0, &c0);
                __sincosf(p * invf1, &s1, &c1);
                const float x0 = acc[ti][0][r], x1 = acc[ti][2][r];
                acc[ti][0][r] = x0 * c0 - x1 * s0;
                acc[ti][2][r] = x1 * c0 + x0 * s0;
                const float y0 = acc[ti][1][r], y1 = acc[ti][3][r];
                acc[ti][1][r] = y0 * c1 - y1 * s1;
                acc[ti][3][r] = y1 * c1 + y0 * s1;
            }
        __bf16* eL = eW;                    // [32][68] bf16, 2 passes
        #pragma unroll
        for (int half = 0; half < 2; ++half) {
            #pragma unroll
            for (int ti = 0; ti < 2; ++ti)
                #pragma unroll
                for (int tj = 0; tj < 4; ++tj)
                    #pragma unroll
                    for (int r = 0; r < 4; ++r)
                        eL[(ti * 16 + fq * 4 + r) * 68 + tj * 16 + fr] =
                            (__bf16)acc[half * 2 + ti][tj][r];
            #pragma unroll
            for (int p = 0; p < 4; ++p) {
                const int rq = p * 8 + (lane >> 3), ch = lane & 7;
                bf16x8 vv = *(const bf16x8*)(eL + rq * 68 + ch * 8);
                *(bf16x8*)(qkv + (size_t)(mm0 + half * 32 + rq) * (2 * D_) + nn0 + ch * 8) = vv;
            }
        }
    } else {
        // v -> vt[b][h][d][token], transposed in LDS, 2 passes over d-halves
        const int h = (nn0 - 2 * D_) >> 6;
        const int bb = mm0 >> 11, t0 = mm0 & (S_ - 1);
        __bf16* eL = eW;                    // [32 d][68 tok] bf16
        const size_t vb = (size_t)((bb * H_ + h) * HD_) * S_ + t0;
        #pragma unroll
        for (int dh = 0; dh < 2; ++dh) {
            #pragma unroll
            for (int tj = 0; tj < 2; ++tj)
                #pragma unroll
                for (int ti = 0; ti < 4; ++ti)
                    #pragma unroll
                    for (int r = 0; r < 4; ++r)
                        eL[(tj * 16 + fr) * 68 + ti * 16 + fq * 4 + r] =
                            (__bf16)acc[ti][dh * 2 + tj][r];
            #pragma unroll
            for (int p = 0; p < 4; ++p) {
                const int d = p * 8 + (lane >> 3), ch = lane & 7;
                bf16x8 vv = *(const bf16x8*)(eL + d * 68 + ch * 8);
                *(bf16x8*)(vt + vb + (size_t)(dh * 32 + d) * S_ + ch * 8) = vv;
            }
        }
    }
}

// ---------------------------------------------------------------------------
// MFMA banded attention (round-9 form: conflict-free LDS via the verified
// chunk-permute/swizzle algebra; values identical, placement swizzled).
// ---------------------------------------------------------------------------
__global__ __launch_bounds__(256) void attn_mfma(const __bf16* __restrict__ qkv,
                                                 const __bf16* __restrict__ vt,
                                                 __bf16* __restrict__ outb) {
    __shared__ __attribute__((aligned(16))) __bf16 smem[24576];  // 48 KB
    __bf16* Ks  = smem;
    __bf16* Vts = smem + 12288;

    const int i0  = blockIdx.x * 64;
    const int h   = blockIdx.y;
    const int b   = blockIdx.z;
    const int tid = threadIdx.x;
    const int w = tid >> 6, lane = tid & 63;
    const int fr = lane & 15, fq = lane >> 4;
    const int sw = (fq + (fr >> 1)) & 3;     // swizzled chunk-in-row
    const int wq0 = w * 16;

    #pragma unroll
    for (int i = 0; i < 6; ++i) {
        int c = i * 256 + tid;
        int ks = (i >= 3);
        int rem = c - ks * 768;
        int ccp = rem & 3, row = rem >> 2;
        int cc = (ccp - (row >> 1)) & 3;                     // source chunk permute
        int j = i0 - 64 + row; j = min(max(j, 0), S_ - 1);   // clamped; masked later
        async_ld16(qkv + ((size_t)b * S_ + j) * (2 * D_) + D_ + h * HD_ + ks * 32 + cc * 8,
                   Ks + c * 8);
    }
    const size_t vbase = (size_t)((b * H_ + h) * HD_) * S_;
    #pragma unroll
    for (int i = 0; i < 6; ++i) {
        int c = i * 256 + tid;
        int ks = c >> 8, rem = c & 255, d = rem >> 2, ccp = rem & 3;
        int cc = (ccp - (d >> 1)) & 3;                       // source chunk permute
        int key = i0 - 64 + ks * 32 + cc * 8;
        key = min(max(key, 0), S_ - 8);                      // clamped; masked later
        async_ld16(vt + vbase + (size_t)d * S_ + key, Vts + c * 8);
    }

    const size_t qrow = ((size_t)b * S_ + i0 + wq0 + fr) * (2 * D_) + h * HD_;
    bf16x8 aq[2];
    aq[0] = *(const bf16x8*)(qkv + qrow + fq * 8);
    aq[1] = *(const bf16x8*)(qkv + qrow + 32 + fq * 8);

    __syncthreads();

    f32x4 sc[12] = {};
    #pragma unroll
    for (int nt = 0; nt < 12; ++nt) {
        #pragma unroll
        for (int ks = 0; ks < 2; ++ks) {
            bf16x8 bk = *(const bf16x8*)(Ks + (ks * 192 + nt * 16 + fr) * 32 + sw * 8);
            sc[nt] = __builtin_amdgcn_mfma_f32_16x16x32_bf16(aq[ks], bk, sc[nt], 0, 0, 0);
        }
    }

    float mx[4] = { -1e30f, -1e30f, -1e30f, -1e30f };
    #pragma unroll
    for (int nt = 0; nt < 12; ++nt) {
        const int jr = nt * 16 + fr;
        const int j  = i0 - 64 + jr;
        const bool jv = (j >= 0) && (j < S_);
        #pragma unroll
        for (int r = 0; r < 4; ++r) {
            const int ir = wq0 + fq * 4 + r + 64;
            const int dd = ir - jr;
            const bool v = jv && (dd <= WIN_) && (dd >= -WIN_);
            sc[nt][r] = v ? sc[nt][r] * 0.125f : -1e30f;
            mx[r] = fmaxf(mx[r], sc[nt][r]);
        }
    }
    #pragma unroll
    for (int r = 0; r < 4; ++r)
        #pragma unroll
        for (int off = 1; off < 16; off <<= 1)
            mx[r] = fmaxf(mx[r], __shfl_xor(mx[r], off, 64));

    float sm[4] = { 0.f, 0.f, 0.f, 0.f };
    #pragma unroll
    for (int nt = 0; nt < 12; ++nt)
        #pragma unroll
        for (int r = 0; r < 4; ++r) {
            float e = __expf(sc[nt][r] - mx[r]);
            sc[nt][r] = e;
            sm[r] += e;
        }
    #pragma unroll
    for (int r = 0; r < 4; ++r) {
        #pragma unroll
        for (int off = 1; off < 16; off <<= 1)
            sm[r] += __shfl_xor(sm[r], off, 64);
        sm[r] = 1.0f / sm[r];
    }

    __syncthreads();

    __bf16* Pw = Ks + w * 3072;
    #pragma unroll
    for (int nt = 0; nt < 12; ++nt) {
        const int ks = nt >> 1, kk = (nt & 1) * 16 + fr;
        const int kc = kk >> 3, kj = kk & 7;
        #pragma unroll
        for (int r = 0; r < 4; ++r) {
            // row = ks*16 + fq*4 + r; place chunk kc at ((kc + (row>>1)) & 3)
            const int pc = (kc + 2 * fq + (r >> 1)) & 3;
            Pw[(ks * 16 + fq * 4 + r) * 32 + pc * 8 + kj] = (__bf16)(sc[nt][r] * sm[r]);
        }
    }

    f32x4 oacc[4] = {};
    #pragma unroll
    for (int ks = 0; ks < 6; ++ks) {
        bf16x8 ap = *(const bf16x8*)(Pw + (ks * 16 + fr) * 32 + sw * 8);
        #pragma unroll
        for (int nt2 = 0; nt2 < 4; ++nt2) {
            bf16x8 bv = *(const bf16x8*)(Vts + (ks * 64 + nt2 * 16 + fr) * 32 + sw * 8);
            oacc[nt2] = __builtin_amdgcn_mfma_f32_16x16x32_bf16(ap, bv, oacc[nt2], 0, 0, 0);
        }
    }

    // O via per-wave LDS bounce (reuse Pw region) -> coalesced 128-B rows
    #pragma unroll
    for (int nt2 = 0; nt2 < 4; ++nt2)
        #pragma unroll
        for (int r = 0; r < 4; ++r)
            Pw[(fq * 4 + r) * 68 + nt2 * 16 + fr] = (__bf16)oacc[nt2][r];
    #pragma unroll
    for (int p = 0; p < 2; ++p) {
        const int q = p * 8 + (lane >> 3), ch = lane & 7;
        bf16x8 vv = *(const bf16x8*)(Pw + q * 68 + ch * 8);
        *(bf16x8*)(outb + ((size_t)b * S_ + i0 + wq0 + q) * D_ + h * HD_ + ch * 8) = vv;
    }
}

// ---------------------------------------------------------------------------
extern "C" void kernel_launch(void* const* d_in, const int* in_sizes, int n_in,
                              void* d_out, int out_size, void* d_ws, size_t ws_size,
                              hipStream_t stream) {
    const float* hs   = (const float*)d_in[0];
    const float* wqkv = (const float*)d_in[1];
    const float* wo   = (const float*)d_in[2];
    const int*   pos  = (const int*)d_in[4];
    float* out = (float*)d_out;

    __bf16* base    = (__bf16*)d_ws;
    __bf16* hs_bf   = base;                          // 3,145,728
    __bf16* wqkv_bf = hs_bf + NHS;                   // 1,769,472
    __bf16* wo_bf   = wqkv_bf + NWQ;                 //   589,824
    __bf16* qkv     = wo_bf + NWO;                   // 4096*1536
    __bf16* vt      = qkv + (size_t)(B_ * S_) * (2 * D_);   // 2*12*64*2048
    __bf16* attn_bf = vt + (size_t)B_ * H_ * HD_ * S_;      // 4096*768

    // 1) fp32 -> bf16
    to_bf16_3<<<(NHS + NWQ + NWO) / 1024, 256, 0, stream>>>(
        hs, wqkv, wo, hs_bf, wqkv_bf, wo_bf);

    // 2) qkv = hs @ Wqkv^T  (RoPE fused -> qkv bf16; v -> vt transposed)
    //    in-block split-K=2: 12 phases/group, 2x DMA streams/block
    gemm_k2<1><<<dim3(32 * (3 * D_ / 128)), 512, 0, stream>>>(
        hs_bf, wqkv_bf, nullptr, qkv, vt, pos, B_ * S_, 3 * D_, D_);

    // 3) banded MFMA attention (conflict-free LDS)
    attn_mfma<<<dim3(S_ / 64, H_, B_), 256, 0, stream>>>(qkv, vt, attn_bf);

    // 4) out = attn @ Wo^T (fp32 out, coalesced epilogue)
    gemm_k2<0><<<dim3(32 * (D_ / 128)), 512, 0, stream>>>(
        attn_bf, wo_bf, out, nullptr, nullptr, nullptr, B_ * S_, D_, D_);
}

// Round 13
// 135.785 us; speedup vs baseline: 1.3543x; 1.0767x over previous
//
#include <hip/hip_runtime.h>
#include <hip/hip_bf16.h>
#include <cmath>

#define B_   2
#define S_   2048
#define D_   768
#define H_   12
#define HD_  64
#define WIN_ 64

typedef __bf16 bf16x8 __attribute__((ext_vector_type(8)));
typedef __bf16 bf16x4 __attribute__((ext_vector_type(4)));
typedef float  f32x4  __attribute__((ext_vector_type(4)));
typedef unsigned int u32;

__device__ __forceinline__ void async_ld16(const void* g, void* l) {
    __builtin_amdgcn_global_load_lds(
        (__attribute__((address_space(1))) void*)(size_t)g,
        (__attribute__((address_space(3))) void*)(u32)(size_t)l,
        16, 0, 0);
}

// ---------------------------------------------------------------------------
// fp32 -> bf16 convert for hs / Wqkv / Wo (one pass)
// ---------------------------------------------------------------------------
#define NHS (B_ * S_ * D_)        // 3145728
#define NWQ (3 * D_ * D_)         // 1769472
#define NWO (D_ * D_)             //  589824

__global__ __launch_bounds__(256) void to_bf16_3(const float* __restrict__ a,
                                                 const float* __restrict__ b,
                                                 const float* __restrict__ c,
                                                 __bf16* __restrict__ oa,
                                                 __bf16* __restrict__ ob,
                                                 __bf16* __restrict__ oc) {
    const int NA = NHS / 4, NB = NWQ / 4;
    int v = blockIdx.x * 256 + threadIdx.x;
    const float* src; __bf16* dst; int idx;
    if (v < NA)           { src = a; dst = oa; idx = v; }
    else if (v < NA + NB) { src = b; dst = ob; idx = v - NA; }
    else                  { src = c; dst = oc; idx = v - NA - NB; }
    float4 x = ((const float4*)src)[idx];
    bf16x4 y = { (__bf16)x.x, (__bf16)x.y, (__bf16)x.z, (__bf16)x.w };
    *(bf16x4*)(dst + (size_t)idx * 4) = y;
}

// ---------------------------------------------------------------------------
// GEMM1: R5 structure verbatim (best measured for g1).
// Block-cooperative 128x128 tile, 2-phase double-buffered LDS staging,
// statically distinct buffers, one __syncthreads per K-step.
// MODE 1: fused RoPE -> qkv bf16 (n<1536); v -> vt bf16^T.
// ---------------------------------------------------------------------------
#define GSTAGE(DA, DB, kk)                                                    \
    { const int k0_ = (kk) << 5;                                              \
      _Pragma("unroll")                                                       \
      for (int i_ = 0; i_ < 2; ++i_) {                                        \
          const int c_ = i_ * 256 + tid;                                      \
          const int row_ = c_ >> 2;                                           \
          const int cc_ = ((c_ & 3) - (row_ >> 1)) & 3;                       \
          async_ld16(A  + (size_t)(m0 + row_) * K + k0_ + cc_ * 8, (DA) + c_ * 8); \
          async_ld16(Bw + (size_t)(n0 + row_) * K + k0_ + cc_ * 8, (DB) + c_ * 8); \
      } }

#define TCOMP(SA, SB)                                                         \
    { bf16x8 af_[4], bf_[4];                                                  \
      _Pragma("unroll")                                                       \
      for (int t_ = 0; t_ < 4; ++t_) {                                        \
          af_[t_] = *(const bf16x8*)((SA) + (wr64 + t_ * 16 + fr) * 32 + sw * 8); \
          bf_[t_] = *(const bf16x8*)((SB) + (wc64 + t_ * 16 + fr) * 32 + sw * 8); \
      }                                                                       \
      _Pragma("unroll")                                                       \
      for (int ti_ = 0; ti_ < 4; ++ti_)                                       \
          _Pragma("unroll")                                                   \
          for (int tj_ = 0; tj_ < 4; ++tj_)                                   \
              acc[ti_][tj_] = __builtin_amdgcn_mfma_f32_16x16x32_bf16(        \
                  af_[ti_], bf_[tj_], acc[ti_][tj_], 0, 0, 0); }

template <int MODE>
__global__ __launch_bounds__(256) void gemm_t(const __bf16* __restrict__ A,
                                              const __bf16* __restrict__ Bw,
                                              float* __restrict__ C,
                                              __bf16* __restrict__ qkv,
                                              __bf16* __restrict__ vt,
                                              const int* __restrict__ pos,
                                              int M, int N, int K) {
    __shared__ __attribute__((aligned(16))) __bf16 sA0[4096];   // 128x32
    __shared__ __attribute__((aligned(16))) __bf16 sB0[4096];
    __shared__ __attribute__((aligned(16))) __bf16 sA1[4096];
    __shared__ __attribute__((aligned(16))) __bf16 sB1[4096];

    const int tid  = threadIdx.x;
    const int w    = tid >> 6;
    const int lane = tid & 63;
    const int id = blockIdx.x;
    const int m0 = (id & 31) << 7;          // m fastest: XCD partitioning
    const int n0 = (id >> 5) << 7;
    const int fr = lane & 15, fq = lane >> 4;
    const int sw = (fq + (fr >> 1)) & 3;    // swizzled chunk-in-row (verified)
    const int wr64 = (w >> 1) * 64, wc64 = (w & 1) * 64;

    f32x4 acc[4][4] = {};

    const int nkw = K >> 5;                 // 24 (even)

    GSTAGE(sA0, sB0, 0)
    __syncthreads();                        // drains tile-0 DMA
    int t = 0;
    for (; t + 2 < nkw; t += 2) {
        GSTAGE(sA1, sB1, t + 1)             // issue next tile (odd)
        TCOMP(sA0, sB0)                     // compute even tile
        __syncthreads();                    // implicit vmcnt(0): odd tile landed
        GSTAGE(sA0, sB0, t + 2)             // issue next tile (even)
        TCOMP(sA1, sB1)                     // compute odd tile
        __syncthreads();
    }
    GSTAGE(sA1, sB1, nkw - 1)
    TCOMP(sA0, sB0)                         // tile nkw-2
    __syncthreads();
    TCOMP(sA1, sB1)                         // tile nkw-1
    __syncthreads();                        // all LDS reads retired -> overlay

    // ---- per-wave epilogue in private 8 KB region (overlays staging) ----
    __bf16* eW = (w == 0) ? sA0 : (w == 1) ? sB0 : (w == 2) ? sA1 : sB1;
    const int mm0 = m0 + wr64, nn0 = n0 + wc64;

    if (MODE == 0) {
        float* eL = (float*)eW;             // [32][64] fp32 = 8192 B, 2 passes
        #pragma unroll
        for (int half = 0; half < 2; ++half) {
            #pragma unroll
            for (int ti = 0; ti < 2; ++ti)
                #pragma unroll
                for (int tj = 0; tj < 4; ++tj)
                    #pragma unroll
                    for (int r = 0; r < 4; ++r)
                        eL[(ti * 16 + fq * 4 + r) * 64 + tj * 16 + fr] =
                            acc[half * 2 + ti][tj][r];
            #pragma unroll
            for (int p = 0; p < 8; ++p) {
                const int rc = p * 4 + (lane >> 4), ch = lane & 15;
                f32x4 vv = *(const f32x4*)(eL + rc * 64 + ch * 4);
                *(f32x4*)(C + (size_t)(mm0 + half * 32 + rc) * N + nn0 + ch * 4) = vv;
            }
        }
    } else if (nn0 < 2 * D_) {
        // fused RoPE on fp32 acc, then bf16 coalesced store (2 passes)
        const float invf0 = __powf(10000.0f, -(float)fr * (1.0f / 32.0f));
        const float invf1 = __powf(10000.0f, -(float)(16 + fr) * (1.0f / 32.0f));
        #pragma unroll
        for (int ti = 0; ti < 4; ++ti)
            #pragma unroll
            for (int r = 0; r < 4; ++r) {
                const int row = mm0 + ti * 16 + fq * 4 + r;
                const float p = (float)pos[row];
                float s0, c0, s1, c1;
                __sincosf(p * invf0, &s0, &c0);
                __sincosf(p * invf1, &s1, &c1);
                const float x0 = acc[ti][0][r], x1 = acc[ti][2][r];
                acc[ti][0][r] = x0 * c0 - x1 * s0;
                acc[ti][2][r] = x1 * c0 + x0 * s0;
                const float y0 = acc[ti][1][r], y1 = acc[ti][3][r];
                acc[ti][1][r] = y0 * c1 - y1 * s1;
                acc[ti][3][r] = y1 * c1 + y0 * s1;
            }
        __bf16* eL = eW;                    // [32][68] bf16, 2 passes
        #pragma unroll
        for (int half = 0; half < 2; ++half) {
            #pragma unroll
            for (int ti = 0; ti < 2; ++ti)
                #pragma unroll
                for (int tj = 0; tj < 4; ++tj)
                    #pragma unroll
                    for (int r = 0; r < 4; ++r)
                        eL[(ti * 16 + fq * 4 + r) * 68 + tj * 16 + fr] =
                            (__bf16)acc[half * 2 + ti][tj][r];
            #pragma unroll
            for (int p = 0; p < 4; ++p) {
                const int rq = p * 8 + (lane >> 3), ch = lane & 7;
                bf16x8 vv = *(const bf16x8*)(eL + rq * 68 + ch * 8);
                *(bf16x8*)(qkv + (size_t)(mm0 + half * 32 + rq) * (2 * D_) + nn0 + ch * 8) = vv;
            }
        }
    } else {
        // v -> vt[b][h][d][token], transposed in LDS, 2 passes over d-halves
        const int h = (nn0 - 2 * D_) >> 6;
        const int bb = mm0 >> 11, t0 = mm0 & (S_ - 1);
        __bf16* eL = eW;                    // [32 d][68 tok] bf16
        const size_t vb = (size_t)((bb * H_ + h) * HD_) * S_ + t0;
        #pragma unroll
        for (int dh = 0; dh < 2; ++dh) {
            #pragma unroll
            for (int tj = 0; tj < 2; ++tj)
                #pragma unroll
                for (int ti = 0; ti < 4; ++ti)
                    #pragma unroll
                    for (int r = 0; r < 4; ++r)
                        eL[(tj * 16 + fr) * 68 + ti * 16 + fq * 4 + r] =
                            (__bf16)acc[ti][dh * 2 + tj][r];
            #pragma unroll
            for (int p = 0; p < 4; ++p) {
                const int d = p * 8 + (lane >> 3), ch = lane & 7;
                bf16x8 vv = *(const bf16x8*)(eL + d * 68 + ch * 8);
                *(bf16x8*)(vt + vb + (size_t)(dh * 32 + d) * S_ + ch * 8) = vv;
            }
        }
    }
}

// ---------------------------------------------------------------------------
// GEMM2: R8's gemm_n verbatim (64x64 tile, 2 waves, 128 threads).
// For N=768 this gives 768 blocks = 3 blocks/CU vs 128^2's 0.75 -- the
// R8 experiment confounded this with a g1 traffic regression; tested here
// in isolation.  MODE 0 only (fp32 C).
// ---------------------------------------------------------------------------
#define GSTAGEN(DA, DB, kk)                                                   \
    { const int k0_ = (kk) << 5;                                              \
      _Pragma("unroll")                                                       \
      for (int i_ = 0; i_ < (BM + 64) / 32; ++i_) {                           \
          const int c_ = i_ * 128 + tid;                                      \
          if (i_ < BM / 32) {                /* A chunks (compile-time) */    \
              const int row_ = c_ >> 2;                                       \
              const int cc_ = ((c_ & 3) - (row_ >> 1)) & 3;                   \
              async_ld16(A + (size_t)(m0 + row_) * K + k0_ + cc_ * 8,         \
                         (DA) + c_ * 8);                                      \
          } else {                           /* B chunks */                   \
              const int cb_ = c_ - BM * 4;                                    \
              const int row_ = cb_ >> 2;                                      \
              const int cc_ = ((cb_ & 3) - (row_ >> 1)) & 3;                  \
              async_ld16(Bw + (size_t)(n0 + row_) * K + k0_ + cc_ * 8,        \
                         (DB) + cb_ * 8);                                     \
          }                                                                   \
      } }

#define TCOMPN(SA, SB)                                                        \
    { bf16x8 af_[MT], bf_[4];                                                 \
      _Pragma("unroll")                                                       \
      for (int t_ = 0; t_ < MT; ++t_)                                         \
          af_[t_] = *(const bf16x8*)((SA) + (wm + t_ * 16 + fr) * 32 + sw * 8); \
      _Pragma("unroll")                                                       \
      for (int t_ = 0; t_ < 4; ++t_)                                          \
          bf_[t_] = *(const bf16x8*)((SB) + (t_ * 16 + fr) * 32 + sw * 8);    \
      _Pragma("unroll")                                                       \
      for (int ti_ = 0; ti_ < MT; ++ti_)                                      \
          _Pragma("unroll")                                                   \
          for (int tj_ = 0; tj_ < 4; ++tj_)                                   \
              acc[ti_][tj_] = __builtin_amdgcn_mfma_f32_16x16x32_bf16(        \
                  af_[ti_], bf_[tj_], acc[ti_][tj_], 0, 0, 0); }

template <int WM>
__global__ __launch_bounds__(128) void gemm_n(const __bf16* __restrict__ A,
                                              const __bf16* __restrict__ Bw,
                                              float* __restrict__ C,
                                              int M, int N, int K) {
    constexpr int BM = 2 * WM;            // block rows (2 waves)
    constexpr int MT = WM / 16;           // acc row-frags per wave
    constexpr int PH = (BM + 64) * 64;    // phase bytes: A BM*64 + B 64*64
    __shared__ __attribute__((aligned(16))) char smem[2 * PH];

    const int tid  = threadIdx.x;
    const int w    = tid >> 6;
    const int lane = tid & 63;
    const int id = blockIdx.x;
    constexpr int MTILES = 4096 / BM;
    const int m0 = (id & (MTILES - 1)) * BM;   // m fastest: XCD partitioning
    const int n0 = (id / MTILES) << 6;
    const int fr = lane & 15, fq = lane >> 4;
    const int sw = (fq + (fr >> 1)) & 3;       // swizzled chunk-in-row
    const int wm = w * WM;

    __bf16* As0 = (__bf16*)smem;
    __bf16* Bs0 = As0 + BM * 32;
    __bf16* As1 = (__bf16*)(smem + PH);
    __bf16* Bs1 = As1 + BM * 32;

    f32x4 acc[MT][4] = {};

    const int nkw = K >> 5;                    // 24 (even)

    GSTAGEN(As0, Bs0, 0)
    __syncthreads();                           // tile-0 DMA drained
    int t = 0;
    for (; t + 2 < nkw; t += 2) {
        GSTAGEN(As1, Bs1, t + 1)
        TCOMPN(As0, Bs0)
        __syncthreads();
        GSTAGEN(As0, Bs0, t + 2)
        TCOMPN(As1, Bs1)
        __syncthreads();
    }
    GSTAGEN(As1, Bs1, nkw - 1)
    TCOMPN(As0, Bs0)                           // tile nkw-2
    __syncthreads();
    TCOMPN(As1, Bs1)                           // tile nkw-1
    __syncthreads();                           // reads retired -> overlay

    // ---- per-wave epilogue in its phase region (8 KiB) ----
    __bf16* eW = (__bf16*)(smem + w * PH);
    const int mm0 = m0 + wm, nn0 = n0;

    // WM=32: fp32 [32][64] bounce = 8192 B, single pass
    float* eL = (float*)eW;
    #pragma unroll
    for (int ti = 0; ti < MT; ++ti)
        #pragma unroll
        for (int tj = 0; tj < 4; ++tj)
            #pragma unroll
            for (int r = 0; r < 4; ++r)
                eL[(ti * 16 + fq * 4 + r) * 64 + tj * 16 + fr] = acc[ti][tj][r];
    #pragma unroll
    for (int p = 0; p < WM / 4; ++p) {
        const int rc = p * 4 + (lane >> 4), ch = lane & 15;
        f32x4 vv = *(const f32x4*)(eL + rc * 64 + ch * 4);
        *(f32x4*)(C + (size_t)(mm0 + rc) * N + nn0 + ch * 4) = vv;
    }
}

// ---------------------------------------------------------------------------
// MFMA banded attention.  Block = 64 queries x (head, batch), 4 waves.
// LDS (48 KB): Ks [2][192][32] (24 KB, overlaid by P), Vts [6][64][32] (24 KB).
// Q frags direct from global.  O store bounced through LDS (coalesced 128-B).
// ---------------------------------------------------------------------------
__global__ __launch_bounds__(256) void attn_mfma(const __bf16* __restrict__ qkv,
                                                 const __bf16* __restrict__ vt,
                                                 __bf16* __restrict__ outb) {
    __shared__ __attribute__((aligned(16))) __bf16 smem[24576];  // 48 KB
    __bf16* Ks  = smem;
    __bf16* Vts = smem + 12288;

    const int i0  = blockIdx.x * 64;
    const int h   = blockIdx.y;
    const int b   = blockIdx.z;
    const int tid = threadIdx.x;
    const int w = tid >> 6, lane = tid & 63;
    const int fr = lane & 15, fq = lane >> 4;
    const int wq0 = w * 16;

    #pragma unroll
    for (int i = 0; i < 6; ++i) {
        int c = i * 256 + tid;
        int ks = (i >= 3);
        int rem = c - ks * 768;
        int cc = rem & 3, row = rem >> 2;
        int j = i0 - 64 + row; j = min(max(j, 0), S_ - 1);   // clamped; masked later
        async_ld16(qkv + ((size_t)b * S_ + j) * (2 * D_) + D_ + h * HD_ + ks * 32 + cc * 8,
                   Ks + c * 8);
    }
    const size_t vbase = (size_t)((b * H_ + h) * HD_) * S_;
    #pragma unroll
    for (int i = 0; i < 6; ++i) {
        int c = i * 256 + tid;
        int ks = c >> 8, rem = c & 255, d = rem >> 2, cc = rem & 3;
        int key = i0 - 64 + ks * 32 + cc * 8;
        key = min(max(key, 0), S_ - 8);                      // clamped; masked later
        async_ld16(vt + vbase + (size_t)d * S_ + key, Vts + c * 8);
    }

    const size_t qrow = ((size_t)b * S_ + i0 + wq0 + fr) * (2 * D_) + h * HD_;
    bf16x8 aq[2];
    aq[0] = *(const bf16x8*)(qkv + qrow + fq * 8);
    aq[1] = *(const bf16x8*)(qkv + qrow + 32 + fq * 8);

    __syncthreads();

    f32x4 sc[12] = {};
    #pragma unroll
    for (int nt = 0; nt < 12; ++nt) {
        #pragma unroll
        for (int ks = 0; ks < 2; ++ks) {
            bf16x8 bk = *(const bf16x8*)(Ks + (ks * 192 + nt * 16 + fr) * 32 + fq * 8);
            sc[nt] = __builtin_amdgcn_mfma_f32_16x16x32_bf16(aq[ks], bk, sc[nt], 0, 0, 0);
        }
    }

    float mx[4] = { -1e30f, -1e30f, -1e30f, -1e30f };
    #pragma unroll
    for (int nt = 0; nt < 12; ++nt) {
        const int jr = nt * 16 + fr;
        const int j  = i0 - 64 + jr;
        const bool jv = (j >= 0) && (j < S_);
        #pragma unroll
        for (int r = 0; r < 4; ++r) {
            const int ir = wq0 + fq * 4 + r + 64;
            const int dd = ir - jr;
            const bool v = jv && (dd <= WIN_) && (dd >= -WIN_);
            sc[nt][r] = v ? sc[nt][r] * 0.125f : -1e30f;
            mx[r] = fmaxf(mx[r], sc[nt][r]);
        }
    }
    #pragma unroll
    for (int r = 0; r < 4; ++r)
        #pragma unroll
        for (int off = 1; off < 16; off <<= 1)
            mx[r] = fmaxf(mx[r], __shfl_xor(mx[r], off, 64));

    float sm[4] = { 0.f, 0.f, 0.f, 0.f };
    #pragma unroll
    for (int nt = 0; nt < 12; ++nt)
        #pragma unroll
        for (int r = 0; r < 4; ++r) {
            float e = __expf(sc[nt][r] - mx[r]);
            sc[nt][r] = e;
            sm[r] += e;
        }
    #pragma unroll
    for (int r = 0; r < 4; ++r) {
        #pragma unroll
        for (int off = 1; off < 16; off <<= 1)
            sm[r] += __shfl_xor(sm[r], off, 64);
        sm[r] = 1.0f / sm[r];
    }

    __syncthreads();

    __bf16* Pw = Ks + w * 3072;
    #pragma unroll
    for (int nt = 0; nt < 12; ++nt) {
        const int ks = nt >> 1, kk = (nt & 1) * 16 + fr;
        #pragma unroll
        for (int r = 0; r < 4; ++r)
            Pw[(ks * 16 + fq * 4 + r) * 32 + kk] = (__bf16)(sc[nt][r] * sm[r]);
    }

    f32x4 oacc[4] = {};
    #pragma unroll
    for (int ks = 0; ks < 6; ++ks) {
        bf16x8 ap = *(const bf16x8*)(Pw + (ks * 16 + fr) * 32 + fq * 8);
        #pragma unroll
        for (int nt2 = 0; nt2 < 4; ++nt2) {
            bf16x8 bv = *(const bf16x8*)(Vts + (ks * 64 + nt2 * 16 + fr) * 32 + fq * 8);
            oacc[nt2] = __builtin_amdgcn_mfma_f32_16x16x32_bf16(ap, bv, oacc[nt2], 0, 0, 0);
        }
    }

    // O via per-wave LDS bounce (reuse Pw region) -> coalesced 128-B rows
    #pragma unroll
    for (int nt2 = 0; nt2 < 4; ++nt2)
        #pragma unroll
        for (int r = 0; r < 4; ++r)
            Pw[(fq * 4 + r) * 68 + nt2 * 16 + fr] = (__bf16)oacc[nt2][r];
    #pragma unroll
    for (int p = 0; p < 2; ++p) {
        const int q = p * 8 + (lane >> 3), ch = lane & 7;
        bf16x8 vv = *(const bf16x8*)(Pw + q * 68 + ch * 8);
        *(bf16x8*)(outb + ((size_t)b * S_ + i0 + wq0 + q) * D_ + h * HD_ + ch * 8) = vv;
    }
}

// ---------------------------------------------------------------------------
extern "C" void kernel_launch(void* const* d_in, const int* in_sizes, int n_in,
                              void* d_out, int out_size, void* d_ws, size_t ws_size,
                              hipStream_t stream) {
    const float* hs   = (const float*)d_in[0];
    const float* wqkv = (const float*)d_in[1];
    const float* wo   = (const float*)d_in[2];
    const int*   pos  = (const int*)d_in[4];
    float* out = (float*)d_out;

    __bf16* base    = (__bf16*)d_ws;
    __bf16* hs_bf   = base;                          // 3,145,728
    __bf16* wqkv_bf = hs_bf + NHS;                   // 1,769,472
    __bf16* wo_bf   = wqkv_bf + NWQ;                 //   589,824
    __bf16* qkv     = wo_bf + NWO;                   // 4096*1536
    __bf16* vt      = qkv + (size_t)(B_ * S_) * (2 * D_);   // 2*12*64*2048
    __bf16* attn_bf = vt + (size_t)B_ * H_ * HD_ * S_;      // 4096*768

    // 1) fp32 -> bf16
    to_bf16_3<<<(NHS + NWQ + NWO) / 1024, 256, 0, stream>>>(
        hs, wqkv, wo, hs_bf, wqkv_bf, wo_bf);

    // 2) qkv = hs @ Wqkv^T  (RoPE fused -> qkv bf16; v -> vt transposed)
    //    R5 structure verbatim (best measured for g1)
    gemm_t<1><<<dim3(32 * (3 * D_ / 128)), 256, 0, stream>>>(
        hs_bf, wqkv_bf, nullptr, qkv, vt, pos, B_ * S_, 3 * D_, D_);

    // 3) banded MFMA attention (R5 form)
    attn_mfma<<<dim3(S_ / 64, H_, B_), 256, 0, stream>>>(qkv, vt, attn_bf);

    // 4) out = attn @ Wo^T (fp32 out)
    //    R8's 64x64-tile gemm_n: 768 blocks = 3 blocks/CU (vs 0.75 at 128^2)
    gemm_n<32><<<dim3(64 * (D_ / 64)), 128, 0, stream>>>(
        attn_bf, wo_bf, out, B_ * S_, D_, D_);
}